// Round 14
// baseline (224.629 us; speedup 1.0000x reference)
//
#include <hip/hip_runtime.h>
#include <hip/hip_bf16.h>
#include <stdint.h>

typedef unsigned short u16;
typedef __attribute__((ext_vector_type(8))) short short8;
typedef __attribute__((ext_vector_type(4))) short s4v;
typedef __attribute__((ext_vector_type(4))) float f32x4;

__device__ __forceinline__ float bf2f(u16 u) {
    union { uint32_t u; float f; } v; v.u = ((uint32_t)u) << 16; return v.f;
}
__device__ __forceinline__ u16 f2bf(float f) {
    union { float f; uint32_t u; } v; v.f = f;
    uint32_t r = (v.u + 0x7fffu + ((v.u >> 16) & 1u)) >> 16;
    return (u16)r;
}
__device__ __forceinline__ uint32_t pkbf(float a, float b) {
    union { __hip_bfloat162 h; uint32_t w; } u;
    u.h = __float22bfloat162_rn(float2{a, b});
    return u.w;
}
__device__ __forceinline__ void store_out(u16* p, float v) { *p = f2bf(v); }
__device__ __forceinline__ void store_out(float* p, float v) { *p = v; }

__device__ __forceinline__ void async_ld16(const u16* g, u16* l) {
    __builtin_amdgcn_global_load_lds(
        (const __attribute__((address_space(1))) void*)g,
        (__attribute__((address_space(3))) void*)l, 16, 0, 0);
}

// ---------------------------------------------------------------------------
// x fp32 [4096*1024] -> bf16
// ---------------------------------------------------------------------------
__global__ void cvt_x(const float* __restrict__ x, u16* __restrict__ xb) {
    int i = (blockIdx.x * 256 + threadIdx.x) * 8;
    float4 a = *(const float4*)(x + i);
    float4 b = *(const float4*)(x + i + 4);
    union { uint32_t w[4]; uint4 v; } o;
    o.w[0] = pkbf(a.x, a.y); o.w[1] = pkbf(a.z, a.w);
    o.w[2] = pkbf(b.x, b.y); o.w[3] = pkbf(b.z, b.w);
    *(uint4*)(xb + i) = o.v;
}

// ---------------------------------------------------------------------------
// fp32 [1024][1024] -> bf16 transposed; z selects among 3 sources
// ---------------------------------------------------------------------------
__global__ void transpose3(const float* __restrict__ w0, const float* __restrict__ w1,
                           const float* __restrict__ w2, u16* __restrict__ out) {
    const int z = blockIdx.z;
    const float* in = (z == 0) ? w0 : (z == 1) ? w1 : w2;
    u16* o = out + (size_t)z * 1024 * 1024;
    __shared__ u16 tile[32][33];
    int x = blockIdx.x * 32 + threadIdx.x;
    int y0 = blockIdx.y * 32;
#pragma unroll
    for (int j = threadIdx.y; j < 32; j += 8)
        tile[j][threadIdx.x] = f2bf(in[(size_t)(y0 + j) * 1024 + x]);
    __syncthreads();
    int ox = blockIdx.y * 32 + threadIdx.x;
    int oy0 = blockIdx.x * 32;
#pragma unroll
    for (int j = threadIdx.y; j < 32; j += 8)
        o[(size_t)(oy0 + j) * 1024 + ox] = tile[threadIdx.x][j];
}

// ---------------------------------------------------------------------------
// GEMM (B^T bf16, async-LDS staging, BK=32, no-pad [128][32]). 128x128 tile.
// ---------------------------------------------------------------------------
#define GBM 128
#define GBN 128
#define GBK 32

template <typename OutT>
__global__ __launch_bounds__(256) void gemm_bt(
    const u16* __restrict__ A, int lda,
    const u16* __restrict__ BT, int ldb,
    const float* __restrict__ bias0, const float* __restrict__ bias1,
    const float* __restrict__ bias2,
    OutT* __restrict__ C, int ldc, int K) {
    __shared__ __align__(16) u16 As[GBM * GBK];
    __shared__ __align__(16) u16 Bs[GBN * GBK];

    const int tid = threadIdx.x;
    const int wave = tid >> 6, lane = tid & 63;
    const int quad = lane >> 4, l16 = lane & 15;
    const int wr = wave >> 1, wc = wave & 1;
    const int m0 = blockIdx.y * GBM, n0 = blockIdx.x * GBN;

    const int seg = n0 >> 10;
    const float* bsel = (seg == 0) ? bias0 : (seg == 1) ? bias1 : bias2;

    f32x4 acc[4][4] = {};

    const int srow = tid >> 2;
    const int scol = (tid & 3) * 8;
    const u16* Ag0 = A + (size_t)(m0 + srow) * lda + scol;
    const u16* Ag1 = Ag0 + (size_t)64 * lda;
    const u16* Bg0 = BT + (size_t)(n0 + srow) * ldb + scol;
    const u16* Bg1 = Bg0 + (size_t)64 * ldb;
    u16* As0 = As + (wave << 9);
    u16* As1 = As0 + 64 * GBK;
    u16* Bs0 = Bs + (wave << 9);
    u16* Bs1 = Bs0 + 64 * GBK;

    for (int kb = 0; kb < K; kb += GBK) {
        async_ld16(Ag0 + kb, As0);
        async_ld16(Ag1 + kb, As1);
        async_ld16(Bg0 + kb, Bs0);
        async_ld16(Bg1 + kb, Bs1);
        __syncthreads();

        short8 af[4], bf[4];
#pragma unroll
        for (int mt = 0; mt < 4; mt++)
            af[mt] = *(const short8*)(As + (wr * 64 + mt * 16 + l16) * GBK + quad * 8);
#pragma unroll
        for (int nt = 0; nt < 4; nt++)
            bf[nt] = *(const short8*)(Bs + (wc * 64 + nt * 16 + l16) * GBK + quad * 8);
#pragma unroll
        for (int mt = 0; mt < 4; mt++)
#pragma unroll
            for (int nt = 0; nt < 4; nt++)
                acc[mt][nt] = __builtin_amdgcn_mfma_f32_16x16x32_bf16(
                    af[mt], bf[nt], acc[mt][nt], 0, 0, 0);
        __syncthreads();
    }

#pragma unroll
    for (int nt = 0; nt < 4; nt++) {
        int col = n0 + wc * 64 + nt * 16 + l16;
        float bv = bsel[col & 1023];
#pragma unroll
        for (int mt = 0; mt < 4; mt++) {
            int row = m0 + wr * 64 + mt * 16 + quad * 4;
#pragma unroll
            for (int r = 0; r < 4; r++)
                store_out(&C[(size_t)(row + r) * ldc + col], acc[mt][nt][r] + bv);
        }
    }
}

// ---------------------------------------------------------------------------
// Flash attention, KV-split=2: grid (16,16,4), z = bb + 2*half. Each block
// does 8 of 16 KV iters -> 1024 blocks = 4/CU (2x occupancy vs r11/r13).
// No online max => partials combine additively: half 0 writes unnormalized
// O to Opart, half 1 to the Q region; both store l to lpart. BQ=128
// (2 q-slabs/wave), transposed-MFMA, zero P movement, 2 barriers/iter.
// ---------------------------------------------------------------------------
#define SEQ 2048
#define BQT 128
#define BKV 128
#define LDK 72     // Ks row: 64 d + 8 pad
#define LDKV 136   // Vs row: 128 kk + 8 pad

__global__ __launch_bounds__(256) void attn(u16* __restrict__ QKV,
                                            u16* __restrict__ Opart,
                                            float* __restrict__ lpart) {
    __shared__ __align__(16) u16 Ks[BKV * LDK];        // [kk][d]
    __shared__ __align__(16) u16 Vs[64 * LDKV];        // [d][kk] (transposed)

    const int tid = threadIdx.x;
    const int wave = tid >> 6, lane = tid & 63;
    const int quad = lane >> 4, l16 = lane & 15;
    const int h = blockIdx.y;
    const int bb = blockIdx.z & 1, half = blockIdx.z >> 1;
    const int q0 = blockIdx.x * BQT;
    const size_t tok0 = (size_t)bb * SEQ;
    const int kv0 = half * (SEQ / 2);

    const u16* Qb = QKV + tok0 * 3072 + h * 64;
    const u16* Kb = QKV + tok0 * 3072 + 1024 + h * 64;
    const u16* Vb = QKV + tok0 * 3072 + 2048 + h * 64;

    const float cs = 0.18033688011112042f;  // (1/8) * log2(e)

    int qr[2];
    qr[0] = q0 + wave * 16 + l16;
    qr[1] = qr[0] + 64;
    short8 aq[2][2];
#pragma unroll
    for (int s = 0; s < 2; s++) {
        union { short8 v; u16 u[8]; uint32_t w[4]; } qa, qb;
        qa.v = *(const short8*)(Qb + (size_t)qr[s] * 3072 + quad * 8);
        qb.v = *(const short8*)(Qb + (size_t)qr[s] * 3072 + 32 + quad * 8);
#pragma unroll
        for (int j = 0; j < 4; j++) {
            qa.w[j] = pkbf(bf2f(qa.u[2 * j]) * cs, bf2f(qa.u[2 * j + 1]) * cs);
            qb.w[j] = pkbf(bf2f(qb.u[2 * j]) * cs, bf2f(qb.u[2 * j + 1]) * cs);
        }
        aq[s][0] = qa.v; aq[s][1] = qb.v;
    }

    float l_i[2] = {0.0f, 0.0f};
    f32x4 o[2][4] = {};

    const int srow = tid >> 2;           // 0..63
    const int scc = (tid & 3) * 16;      // 0/16/32/48
    const int pr = tid & 63;
    const int dg = wave;

    const u16* kg = Kb + (size_t)(kv0 + srow) * 3072 + scc;
    const u16* vg = Vb + (size_t)(kv0 + 2 * pr) * 3072 + dg * 16;

    uint4 k0r = *(const uint4*)(kg);
    uint4 k1r = *(const uint4*)(kg + 8);
    uint4 k2r = *(const uint4*)(kg + (size_t)64 * 3072);
    uint4 k3r = *(const uint4*)(kg + (size_t)64 * 3072 + 8);
    uint4 va0 = *(const uint4*)(vg);
    uint4 va1 = *(const uint4*)(vg + 8);
    uint4 vb0 = *(const uint4*)(vg + 3072);
    uint4 vb1 = *(const uint4*)(vg + 3072 + 8);

    for (int j0 = 0; j0 < SEQ / 2; j0 += BKV) {
        *(uint4*)(Ks + srow * LDK + scc) = k0r;
        *(uint4*)(Ks + srow * LDK + scc + 8) = k1r;
        *(uint4*)(Ks + (srow + 64) * LDK + scc) = k2r;
        *(uint4*)(Ks + (srow + 64) * LDK + scc + 8) = k3r;
        {
            union { uint4 v[2]; u16 u[16]; } a, b;
            a.v[0] = va0; a.v[1] = va1; b.v[0] = vb0; b.v[1] = vb1;
#pragma unroll
            for (int j = 0; j < 16; j++) {
                uint32_t w = (uint32_t)a.u[j] | ((uint32_t)b.u[j] << 16);
                *(uint32_t*)(Vs + (dg * 16 + j) * LDKV + 2 * pr) = w;
            }
        }
        __syncthreads();   // B1: staged tile visible

        if (j0 + BKV < SEQ / 2) {
            size_t off = (size_t)(j0 + BKV) * 3072;
            k0r = *(const uint4*)(kg + off);
            k1r = *(const uint4*)(kg + off + 8);
            k2r = *(const uint4*)(kg + off + (size_t)64 * 3072);
            k3r = *(const uint4*)(kg + off + (size_t)64 * 3072 + 8);
            va0 = *(const uint4*)(vg + off);
            va1 = *(const uint4*)(vg + off + 8);
            vb0 = *(const uint4*)(vg + off + 3072);
            vb1 = *(const uint4*)(vg + off + 3072 + 8);
        }

        f32x4 st[2][8];
#pragma unroll
        for (int kkt = 0; kkt < 8; kkt++) {
            f32x4 s0 = {}, s1 = {};
#pragma unroll
            for (int k2 = 0; k2 < 2; k2++) {
                short8 ak = *(const short8*)(Ks + (kkt * 16 + l16) * LDK + k2 * 32 + quad * 8);
                s0 = __builtin_amdgcn_mfma_f32_16x16x32_bf16(ak, aq[0][k2], s0, 0, 0, 0);
                s1 = __builtin_amdgcn_mfma_f32_16x16x32_bf16(ak, aq[1][k2], s1, 0, 0, 0);
            }
            st[0][kkt] = s0; st[1][kkt] = s1;
        }

#pragma unroll
        for (int s = 0; s < 2; s++) {
            float ls = 0.0f;
#pragma unroll
            for (int kkt = 0; kkt < 8; kkt++)
#pragma unroll
                for (int r = 0; r < 4; r++) {
                    st[s][kkt][r] = __builtin_amdgcn_exp2f(st[s][kkt][r]);
                    ls += st[s][kkt][r];
                }
            ls += __shfl_xor(ls, 16, 64);
            ls += __shfl_xor(ls, 32, 64);
            l_i[s] += ls;
        }

#pragma unroll
        for (int kkt = 0; kkt < 8; kkt++) {
            union { uint32_t w[2]; s4v s; } bp0, bp1;
            bp0.w[0] = pkbf(st[0][kkt][0], st[0][kkt][1]);
            bp0.w[1] = pkbf(st[0][kkt][2], st[0][kkt][3]);
            bp1.w[0] = pkbf(st[1][kkt][0], st[1][kkt][1]);
            bp1.w[1] = pkbf(st[1][kkt][2], st[1][kkt][3]);
#pragma unroll
            for (int dt = 0; dt < 4; dt++) {
                s4v av = *(const s4v*)(Vs + (dt * 16 + l16) * LDKV + kkt * 16 + quad * 4);
                o[0][dt] = __builtin_amdgcn_mfma_f32_16x16x16bf16_1k(av, bp0.s, o[0][dt], 0, 0, 0);
                o[1][dt] = __builtin_amdgcn_mfma_f32_16x16x16bf16_1k(av, bp1.s, o[1][dt], 0, 0, 0);
            }
        }

        __syncthreads();   // B2: Ks/Vs reads done before next staging
    }

    // ---- write unnormalized partial O + l (combine kernel normalizes) ----
#pragma unroll
    for (int s = 0; s < 2; s++) {
        u16* obase = half ? (QKV + (tok0 + qr[s]) * 3072 + h * 64)
                          : (Opart + (tok0 + qr[s]) * 1024 + h * 64);
#pragma unroll
        for (int dt = 0; dt < 4; dt++) {
            uint32_t w0 = pkbf(o[s][dt][0], o[s][dt][1]);
            uint32_t w1 = pkbf(o[s][dt][2], o[s][dt][3]);
            uint2 w = {w0, w1};
            *(uint2*)(obase + dt * 16 + quad * 4) = w;
        }
        if (quad == 0)
            lpart[(size_t)half * 4096 * 16 + (tok0 + qr[s]) * 16 + h] = l_i[s];
    }
}

// ---------------------------------------------------------------------------
// Combine: Q_region[t][c] = (Opart[t][c] + Q_region[t][c]) / (l0+l1)
// 8 cols/thread (within one head). 2048 x 256.
// ---------------------------------------------------------------------------
__global__ __launch_bounds__(256) void combine(u16* __restrict__ QKV,
                                               const u16* __restrict__ Opart,
                                               const float* __restrict__ lpart) {
    int gid = blockIdx.x * 256 + threadIdx.x;     // 0 .. 524287
    int t = gid >> 7;
    int c8 = (gid & 127) * 8;
    int h = c8 >> 6;
    float l0 = lpart[(size_t)t * 16 + h];
    float l1 = lpart[(size_t)4096 * 16 + (size_t)t * 16 + h];
    float inv = 1.0f / (l0 + l1);
    union { uint4 v; u16 u[8]; } a, b, o;
    a.v = *(const uint4*)(Opart + (size_t)t * 1024 + c8);
    u16* qp = QKV + (size_t)t * 3072 + c8;
    b.v = *(const uint4*)(qp);
    union { uint32_t w[4]; uint4 v; } ov;
#pragma unroll
    for (int j = 0; j < 4; j++)
        ov.w[j] = pkbf((bf2f(a.u[2 * j]) + bf2f(b.u[2 * j])) * inv,
                       (bf2f(a.u[2 * j + 1]) + bf2f(b.u[2 * j + 1])) * inv);
    *(uint4*)(qp) = ov.v;
}

// ---------------------------------------------------------------------------
extern "C" void kernel_launch(void* const* d_in, const int* in_sizes, int n_in,
                              void* d_out, int out_size, void* d_ws, size_t ws_size,
                              hipStream_t stream) {
    const float* x  = (const float*)d_in[0];
    const float* wq = (const float*)d_in[1];
    const float* bq = (const float*)d_in[2];
    const float* wk = (const float*)d_in[3];
    const float* bk = (const float*)d_in[4];
    const float* wv = (const float*)d_in[5];
    const float* bv = (const float*)d_in[6];
    const float* wo = (const float*)d_in[7];
    const float* bo = (const float*)d_in[8];
    (void)in_sizes; (void)n_in; (void)out_size; (void)ws_size;

    // ws layout (u16 units): [0,12.58M) QKV | [12.58M,15.73M) wT | [15.73M,19.92M) xb
    // After gemm1: wT+xb head reused as Opart (4M) + lpart; woT at xb tail.
    u16* QKV = (u16*)d_ws;                                   // 24 MB
    u16* wT  = QKV + (size_t)4096 * 3072;                    // 6 MB (dead after gemm1)
    u16* xb  = wT + (size_t)3 * 1024 * 1024;                 // 8 MB (dead after gemm1)
    u16* Opart = wT;                                         // 8 MB = wT + xb[0..1M)
    float* lpart = (float*)(Opart + (size_t)4096 * 1024);    // 512 KB, xb[1M..1.26M)
    u16* woT = xb + (size_t)3 * 1024 * 1024;                 // 2 MB, xb tail

    cvt_x<<<dim3(2048), dim3(256), 0, stream>>>(x, xb);
    transpose3<<<dim3(32, 32, 3), dim3(32, 8), 0, stream>>>(wq, wk, wv, wT);
    gemm_bt<u16><<<dim3(24, 32), 256, 0, stream>>>(xb, 1024, wT, 1024, bq, bk, bv,
                                                   QKV, 3072, 1024);
    transpose3<<<dim3(32, 32, 1), dim3(32, 8), 0, stream>>>(wo, wo, wo, woT);
    attn<<<dim3(16, 16, 4), 256, 0, stream>>>(QKV, Opart, lpart);
    combine<<<dim3(2048), dim3(256), 0, stream>>>(QKV, Opart, lpart);
    gemm_bt<float><<<dim3(8, 32), 256, 0, stream>>>(QKV, 3072, woT, 1024, bo, bo, bo,
                                                    (float*)d_out, 1024, 1024);
}

// Round 15
// 215.669 us; speedup vs baseline: 1.0415x; 1.0415x over previous
//
#include <hip/hip_runtime.h>
#include <hip/hip_bf16.h>
#include <stdint.h>

typedef unsigned short u16;
typedef __attribute__((ext_vector_type(8))) short short8;
typedef __attribute__((ext_vector_type(4))) short s4v;
typedef __attribute__((ext_vector_type(4))) float f32x4;

__device__ __forceinline__ float bf2f(u16 u) {
    union { uint32_t u; float f; } v; v.u = ((uint32_t)u) << 16; return v.f;
}
__device__ __forceinline__ u16 f2bf(float f) {
    union { float f; uint32_t u; } v; v.f = f;
    uint32_t r = (v.u + 0x7fffu + ((v.u >> 16) & 1u)) >> 16;
    return (u16)r;
}
__device__ __forceinline__ uint32_t pkbf(float a, float b) {
    union { __hip_bfloat162 h; uint32_t w; } u;
    u.h = __float22bfloat162_rn(float2{a, b});
    return u.w;
}
__device__ __forceinline__ void store_out(u16* p, float v) { *p = f2bf(v); }
__device__ __forceinline__ void store_out(float* p, float v) { *p = v; }

__device__ __forceinline__ void async_ld16(const u16* g, u16* l) {
    __builtin_amdgcn_global_load_lds(
        (const __attribute__((address_space(1))) void*)g,
        (__attribute__((address_space(3))) void*)l, 16, 0, 0);
}

// ---------------------------------------------------------------------------
// prep: z<3 -> transpose wq/wk/wv fp32 [1024][1024] -> bf16 wT[z][N][K];
//       z>=3 -> cvt x fp32 -> bf16 (chunk z-3 of 2).
// ---------------------------------------------------------------------------
__global__ void prep(const float* __restrict__ x,
                     const float* __restrict__ w0, const float* __restrict__ w1,
                     const float* __restrict__ w2,
                     u16* __restrict__ xb, u16* __restrict__ wT) {
    const int z = blockIdx.z;
    __shared__ u16 tile[32][33];
    if (z >= 3) {
        int blk = (z - 3) * 1024 + blockIdx.y * 32 + blockIdx.x;
        int tid = threadIdx.y * 32 + threadIdx.x;
        int i = (blk * 256 + tid) * 8;
        float4 a = *(const float4*)(x + i);
        float4 b = *(const float4*)(x + i + 4);
        union { uint32_t w[4]; uint4 v; } o;
        o.w[0] = pkbf(a.x, a.y); o.w[1] = pkbf(a.z, a.w);
        o.w[2] = pkbf(b.x, b.y); o.w[3] = pkbf(b.z, b.w);
        *(uint4*)(xb + i) = o.v;
        return;
    }
    const float* in = (z == 0) ? w0 : (z == 1) ? w1 : w2;
    u16* o = wT + (size_t)z * 1024 * 1024;
    int xx = blockIdx.x * 32 + threadIdx.x;
    int y0 = blockIdx.y * 32;
#pragma unroll
    for (int j = threadIdx.y; j < 32; j += 8)
        tile[j][threadIdx.x] = f2bf(in[(size_t)(y0 + j) * 1024 + xx]);
    __syncthreads();
    int ox = blockIdx.y * 32 + threadIdx.x;
    int oy0 = blockIdx.x * 32;
#pragma unroll
    for (int j = threadIdx.y; j < 32; j += 8)
        o[(size_t)(oy0 + j) * 1024 + ox] = tile[threadIdx.x][j];
}

// single-plane weight transpose (for wo, after gemm1 frees xb)
__global__ void transpose1(const float* __restrict__ w, u16* __restrict__ out) {
    __shared__ u16 tile[32][33];
    int x = blockIdx.x * 32 + threadIdx.x;
    int y0 = blockIdx.y * 32;
#pragma unroll
    for (int j = threadIdx.y; j < 32; j += 8)
        tile[j][threadIdx.x] = f2bf(w[(size_t)(y0 + j) * 1024 + x]);
    __syncthreads();
    int ox = blockIdx.y * 32 + threadIdx.x;
    int oy0 = blockIdx.x * 32;
#pragma unroll
    for (int j = threadIdx.y; j < 32; j += 8)
        out[(size_t)(oy0 + j) * 1024 + ox] = tile[threadIdx.x][j];
}

// ---------------------------------------------------------------------------
// GEMM (B^T bf16, async-LDS staging, BK=32, no-pad [128][32]). 128x128 tile.
// ---------------------------------------------------------------------------
#define GBM 128
#define GBN 128
#define GBK 32

template <typename OutT>
__global__ __launch_bounds__(256) void gemm_bt(
    const u16* __restrict__ A, int lda,
    const u16* __restrict__ BT, int ldb,
    const float* __restrict__ bias0, const float* __restrict__ bias1,
    const float* __restrict__ bias2,
    OutT* __restrict__ C, int ldc, int K) {
    __shared__ __align__(16) u16 As[GBM * GBK];
    __shared__ __align__(16) u16 Bs[GBN * GBK];

    const int tid = threadIdx.x;
    const int wave = tid >> 6, lane = tid & 63;
    const int quad = lane >> 4, l16 = lane & 15;
    const int wr = wave >> 1, wc = wave & 1;
    const int m0 = blockIdx.y * GBM, n0 = blockIdx.x * GBN;

    const int seg = n0 >> 10;
    const float* bsel = (seg == 0) ? bias0 : (seg == 1) ? bias1 : bias2;

    f32x4 acc[4][4] = {};

    const int srow = tid >> 2;
    const int scol = (tid & 3) * 8;
    const u16* Ag0 = A + (size_t)(m0 + srow) * lda + scol;
    const u16* Ag1 = Ag0 + (size_t)64 * lda;
    const u16* Bg0 = BT + (size_t)(n0 + srow) * ldb + scol;
    const u16* Bg1 = Bg0 + (size_t)64 * ldb;
    u16* As0 = As + (wave << 9);
    u16* As1 = As0 + 64 * GBK;
    u16* Bs0 = Bs + (wave << 9);
    u16* Bs1 = Bs0 + 64 * GBK;

    for (int kb = 0; kb < K; kb += GBK) {
        async_ld16(Ag0 + kb, As0);
        async_ld16(Ag1 + kb, As1);
        async_ld16(Bg0 + kb, Bs0);
        async_ld16(Bg1 + kb, Bs1);
        __syncthreads();

        short8 af[4], bf[4];
#pragma unroll
        for (int mt = 0; mt < 4; mt++)
            af[mt] = *(const short8*)(As + (wr * 64 + mt * 16 + l16) * GBK + quad * 8);
#pragma unroll
        for (int nt = 0; nt < 4; nt++)
            bf[nt] = *(const short8*)(Bs + (wc * 64 + nt * 16 + l16) * GBK + quad * 8);
#pragma unroll
        for (int mt = 0; mt < 4; mt++)
#pragma unroll
            for (int nt = 0; nt < 4; nt++)
                acc[mt][nt] = __builtin_amdgcn_mfma_f32_16x16x32_bf16(
                    af[mt], bf[nt], acc[mt][nt], 0, 0, 0);
        __syncthreads();
    }

#pragma unroll
    for (int nt = 0; nt < 4; nt++) {
        int col = n0 + wc * 64 + nt * 16 + l16;
        float bv = bsel[col & 1023];
#pragma unroll
        for (int mt = 0; mt < 4; mt++) {
            int row = m0 + wr * 64 + mt * 16 + quad * 4;
#pragma unroll
            for (int r = 0; r < 4; r++)
                store_out(&C[(size_t)(row + r) * ldc + col], acc[mt][nt][r] + bv);
        }
    }
}

// ---------------------------------------------------------------------------
// Flash attention (r11 structure): BQ=128, 2 q-slabs/wave, transposed-MFMA,
// zero P movement, BKV=128, 2 barriers/iter, no online max. ls shuffle
// reduction deferred past the PV MFMAs (overlaps MFMA drain).
// ---------------------------------------------------------------------------
#define SEQ 2048
#define BQT 128
#define BKV 128
#define LDK 72     // Ks row: 64 d + 8 pad
#define LDKV 136   // Vs row: 128 kk + 8 pad

__global__ __launch_bounds__(256) void attn(u16* __restrict__ QKV) {
    __shared__ __align__(16) u16 Ks[BKV * LDK];        // [kk][d]
    __shared__ __align__(16) u16 Vs[64 * LDKV];        // [d][kk] (transposed)

    const int tid = threadIdx.x;
    const int wave = tid >> 6, lane = tid & 63;
    const int quad = lane >> 4, l16 = lane & 15;
    const int h = blockIdx.y, bb = blockIdx.z;
    const int q0 = blockIdx.x * BQT;
    const size_t tok0 = (size_t)bb * SEQ;

    const u16* Qb = QKV + tok0 * 3072 + h * 64;
    const u16* Kb = QKV + tok0 * 3072 + 1024 + h * 64;
    const u16* Vb = QKV + tok0 * 3072 + 2048 + h * 64;

    const float cs = 0.18033688011112042f;  // (1/8) * log2(e)

    int qr[2];
    qr[0] = q0 + wave * 16 + l16;
    qr[1] = qr[0] + 64;
    short8 aq[2][2];
#pragma unroll
    for (int s = 0; s < 2; s++) {
        union { short8 v; u16 u[8]; uint32_t w[4]; } qa, qb;
        qa.v = *(const short8*)(Qb + (size_t)qr[s] * 3072 + quad * 8);
        qb.v = *(const short8*)(Qb + (size_t)qr[s] * 3072 + 32 + quad * 8);
#pragma unroll
        for (int j = 0; j < 4; j++) {
            qa.w[j] = pkbf(bf2f(qa.u[2 * j]) * cs, bf2f(qa.u[2 * j + 1]) * cs);
            qb.w[j] = pkbf(bf2f(qb.u[2 * j]) * cs, bf2f(qb.u[2 * j + 1]) * cs);
        }
        aq[s][0] = qa.v; aq[s][1] = qb.v;
    }

    float l_i[2] = {0.0f, 0.0f};
    f32x4 o[2][4] = {};

    const int srow = tid >> 2;           // 0..63
    const int scc = (tid & 3) * 16;      // 0/16/32/48
    const int pr = tid & 63;
    const int dg = wave;

    const u16* kg = Kb + (size_t)srow * 3072 + scc;
    const u16* vg = Vb + (size_t)(2 * pr) * 3072 + dg * 16;

    uint4 k0r = *(const uint4*)(kg);
    uint4 k1r = *(const uint4*)(kg + 8);
    uint4 k2r = *(const uint4*)(kg + (size_t)64 * 3072);
    uint4 k3r = *(const uint4*)(kg + (size_t)64 * 3072 + 8);
    uint4 va0 = *(const uint4*)(vg);
    uint4 va1 = *(const uint4*)(vg + 8);
    uint4 vb0 = *(const uint4*)(vg + 3072);
    uint4 vb1 = *(const uint4*)(vg + 3072 + 8);

    for (int j0 = 0; j0 < SEQ; j0 += BKV) {
        *(uint4*)(Ks + srow * LDK + scc) = k0r;
        *(uint4*)(Ks + srow * LDK + scc + 8) = k1r;
        *(uint4*)(Ks + (srow + 64) * LDK + scc) = k2r;
        *(uint4*)(Ks + (srow + 64) * LDK + scc + 8) = k3r;
        {
            union { uint4 v[2]; u16 u[16]; } a, b;
            a.v[0] = va0; a.v[1] = va1; b.v[0] = vb0; b.v[1] = vb1;
#pragma unroll
            for (int j = 0; j < 16; j++) {
                uint32_t w = (uint32_t)a.u[j] | ((uint32_t)b.u[j] << 16);
                *(uint32_t*)(Vs + (dg * 16 + j) * LDKV + 2 * pr) = w;
            }
        }
        __syncthreads();   // B1: staged tile visible

        if (j0 + BKV < SEQ) {
            size_t off = (size_t)(j0 + BKV) * 3072;
            k0r = *(const uint4*)(kg + off);
            k1r = *(const uint4*)(kg + off + 8);
            k2r = *(const uint4*)(kg + off + (size_t)64 * 3072);
            k3r = *(const uint4*)(kg + off + (size_t)64 * 3072 + 8);
            va0 = *(const uint4*)(vg + off);
            va1 = *(const uint4*)(vg + off + 8);
            vb0 = *(const uint4*)(vg + off + 3072);
            vb1 = *(const uint4*)(vg + off + 3072 + 8);
        }

        f32x4 st[2][8];
#pragma unroll
        for (int kkt = 0; kkt < 8; kkt++) {
            f32x4 s0 = {}, s1 = {};
#pragma unroll
            for (int k2 = 0; k2 < 2; k2++) {
                short8 ak = *(const short8*)(Ks + (kkt * 16 + l16) * LDK + k2 * 32 + quad * 8);
                s0 = __builtin_amdgcn_mfma_f32_16x16x32_bf16(ak, aq[0][k2], s0, 0, 0, 0);
                s1 = __builtin_amdgcn_mfma_f32_16x16x32_bf16(ak, aq[1][k2], s1, 0, 0, 0);
            }
            st[0][kkt] = s0; st[1][kkt] = s1;
        }

        float ls[2];
#pragma unroll
        for (int s = 0; s < 2; s++) {
            float l = 0.0f;
#pragma unroll
            for (int kkt = 0; kkt < 8; kkt++)
#pragma unroll
                for (int r = 0; r < 4; r++) {
                    st[s][kkt][r] = __builtin_amdgcn_exp2f(st[s][kkt][r]);
                    l += st[s][kkt][r];
                }
            ls[s] = l;
        }

#pragma unroll
        for (int kkt = 0; kkt < 8; kkt++) {
            union { uint32_t w[2]; s4v s; } bp0, bp1;
            bp0.w[0] = pkbf(st[0][kkt][0], st[0][kkt][1]);
            bp0.w[1] = pkbf(st[0][kkt][2], st[0][kkt][3]);
            bp1.w[0] = pkbf(st[1][kkt][0], st[1][kkt][1]);
            bp1.w[1] = pkbf(st[1][kkt][2], st[1][kkt][3]);
#pragma unroll
            for (int dt = 0; dt < 4; dt++) {
                s4v av = *(const s4v*)(Vs + (dt * 16 + l16) * LDKV + kkt * 16 + quad * 4);
                o[0][dt] = __builtin_amdgcn_mfma_f32_16x16x16bf16_1k(av, bp0.s, o[0][dt], 0, 0, 0);
                o[1][dt] = __builtin_amdgcn_mfma_f32_16x16x16bf16_1k(av, bp1.s, o[1][dt], 0, 0, 0);
            }
        }

        // deferred cross-lane reduce: overlaps the PV MFMA drain
#pragma unroll
        for (int s = 0; s < 2; s++) {
            ls[s] += __shfl_xor(ls[s], 16, 64);
            ls[s] += __shfl_xor(ls[s], 32, 64);
            l_i[s] += ls[s];
        }

        __syncthreads();   // B2: Ks/Vs reads done before next staging
    }

#pragma unroll
    for (int s = 0; s < 2; s++) {
        const float inv_l = 1.0f / l_i[s];
        u16* orow = QKV + (tok0 + qr[s]) * 3072 + h * 64;
#pragma unroll
        for (int dt = 0; dt < 4; dt++) {
            uint32_t w0 = pkbf(o[s][dt][0] * inv_l, o[s][dt][1] * inv_l);
            uint32_t w1 = pkbf(o[s][dt][2] * inv_l, o[s][dt][3] * inv_l);
            uint2 w = {w0, w1};
            *(uint2*)(orow + dt * 16 + quad * 4) = w;
        }
    }
}

// ---------------------------------------------------------------------------
extern "C" void kernel_launch(void* const* d_in, const int* in_sizes, int n_in,
                              void* d_out, int out_size, void* d_ws, size_t ws_size,
                              hipStream_t stream) {
    const float* x  = (const float*)d_in[0];
    const float* wq = (const float*)d_in[1];
    const float* bq = (const float*)d_in[2];
    const float* wk = (const float*)d_in[3];
    const float* bk = (const float*)d_in[4];
    const float* wv = (const float*)d_in[5];
    const float* bv = (const float*)d_in[6];
    const float* wo = (const float*)d_in[7];
    const float* bo = (const float*)d_in[8];
    (void)in_sizes; (void)n_in; (void)out_size; (void)ws_size;

    u16* QKV = (u16*)d_ws;                              // [4096][3072] bf16, 24 MB
    u16* wT  = QKV + (size_t)4096 * 3072;               // [3][1024][1024] bf16, 6 MB
    u16* xb  = wT + (size_t)3 * 1024 * 1024;            // [4096][1024] bf16, 8 MB
    u16* woT = xb;                                      // reuses xb after gemm1

    prep<<<dim3(32, 32, 5), dim3(32, 8), 0, stream>>>(x, wq, wk, wv, xb, wT);
    gemm_bt<u16><<<dim3(24, 32), 256, 0, stream>>>(xb, 1024, wT, 1024, bq, bk, bv,
                                                   QKV, 3072, 1024);
    transpose1<<<dim3(32, 32), dim3(32, 8), 0, stream>>>(wo, woT);
    attn<<<dim3(16, 16, 2), 256, 0, stream>>>(QKV);
    gemm_bt<float><<<dim3(8, 32), 256, 0, stream>>>(QKV, 3072, woT, 1024, bo, bo, bo,
                                                    (float*)d_out, 1024, 1024);
}

// Round 16
// 208.812 us; speedup vs baseline: 1.0757x; 1.0328x over previous
//
#include <hip/hip_runtime.h>
#include <hip/hip_bf16.h>
#include <stdint.h>

typedef unsigned short u16;
typedef __attribute__((ext_vector_type(8))) short short8;
typedef __attribute__((ext_vector_type(4))) short s4v;
typedef __attribute__((ext_vector_type(4))) float f32x4;

__device__ __forceinline__ float bf2f(u16 u) {
    union { uint32_t u; float f; } v; v.u = ((uint32_t)u) << 16; return v.f;
}
__device__ __forceinline__ u16 f2bf(float f) {
    union { float f; uint32_t u; } v; v.f = f;
    uint32_t r = (v.u + 0x7fffu + ((v.u >> 16) & 1u)) >> 16;
    return (u16)r;
}
__device__ __forceinline__ uint32_t pkbf(float a, float b) {
    union { __hip_bfloat162 h; uint32_t w; } u;
    u.h = __float22bfloat162_rn(float2{a, b});
    return u.w;
}
__device__ __forceinline__ void store_out(u16* p, float v) { *p = f2bf(v); }
__device__ __forceinline__ void store_out(float* p, float v) { *p = v; }

__device__ __forceinline__ void async_ld16(const u16* g, u16* l) {
    __builtin_amdgcn_global_load_lds(
        (const __attribute__((address_space(1))) void*)g,
        (__attribute__((address_space(3))) void*)l, 16, 0, 0);
}

// ---------------------------------------------------------------------------
// prep: z<3 -> transpose wq/wk/wv fp32 [1024][1024] -> bf16 wT[z][N][K];
//       z>=3 -> cvt x fp32 -> bf16 (chunk z-3 of 2).
// ---------------------------------------------------------------------------
__global__ void prep(const float* __restrict__ x,
                     const float* __restrict__ w0, const float* __restrict__ w1,
                     const float* __restrict__ w2,
                     u16* __restrict__ xb, u16* __restrict__ wT) {
    const int z = blockIdx.z;
    __shared__ u16 tile[32][33];
    if (z >= 3) {
        int blk = (z - 3) * 1024 + blockIdx.y * 32 + blockIdx.x;
        int tid = threadIdx.y * 32 + threadIdx.x;
        int i = (blk * 256 + tid) * 8;
        float4 a = *(const float4*)(x + i);
        float4 b = *(const float4*)(x + i + 4);
        union { uint32_t w[4]; uint4 v; } o;
        o.w[0] = pkbf(a.x, a.y); o.w[1] = pkbf(a.z, a.w);
        o.w[2] = pkbf(b.x, b.y); o.w[3] = pkbf(b.z, b.w);
        *(uint4*)(xb + i) = o.v;
        return;
    }
    const float* in = (z == 0) ? w0 : (z == 1) ? w1 : w2;
    u16* o = wT + (size_t)z * 1024 * 1024;
    int xx = blockIdx.x * 32 + threadIdx.x;
    int y0 = blockIdx.y * 32;
#pragma unroll
    for (int j = threadIdx.y; j < 32; j += 8)
        tile[j][threadIdx.x] = f2bf(in[(size_t)(y0 + j) * 1024 + xx]);
    __syncthreads();
    int ox = blockIdx.y * 32 + threadIdx.x;
    int oy0 = blockIdx.x * 32;
#pragma unroll
    for (int j = threadIdx.y; j < 32; j += 8)
        o[(size_t)(oy0 + j) * 1024 + ox] = tile[threadIdx.x][j];
}

// single-plane weight transpose (for wo, after gemm1 frees xb)
__global__ void transpose1(const float* __restrict__ w, u16* __restrict__ out) {
    __shared__ u16 tile[32][33];
    int x = blockIdx.x * 32 + threadIdx.x;
    int y0 = blockIdx.y * 32;
#pragma unroll
    for (int j = threadIdx.y; j < 32; j += 8)
        tile[j][threadIdx.x] = f2bf(w[(size_t)(y0 + j) * 1024 + x]);
    __syncthreads();
    int ox = blockIdx.y * 32 + threadIdx.x;
    int oy0 = blockIdx.x * 32;
#pragma unroll
    for (int j = threadIdx.y; j < 32; j += 8)
        out[(size_t)(oy0 + j) * 1024 + ox] = tile[threadIdx.x][j];
}

// ---------------------------------------------------------------------------
// GEMM (B^T bf16): double-buffered async-LDS staging, ONE barrier per K-iter.
// Prefetch for tile k+1 is issued right after the barrier and drains at the
// next barrier -- its latency overlaps the 16 MFMAs of tile k. No WAR hazard
// between buffers, so the second barrier of the classic loop is deleted.
// 128x128 tile, BK=32, no-pad [128][32] LDS per buffer.
// ---------------------------------------------------------------------------
#define GBM 128
#define GBN 128
#define GBK 32

template <typename OutT>
__global__ __launch_bounds__(256) void gemm_bt(
    const u16* __restrict__ A, int lda,
    const u16* __restrict__ BT, int ldb,
    const float* __restrict__ bias0, const float* __restrict__ bias1,
    const float* __restrict__ bias2,
    OutT* __restrict__ C, int ldc, int K) {
    __shared__ __align__(16) u16 As[2][GBM * GBK];
    __shared__ __align__(16) u16 Bs[2][GBN * GBK];

    const int tid = threadIdx.x;
    const int wave = tid >> 6, lane = tid & 63;
    const int quad = lane >> 4, l16 = lane & 15;
    const int wr = wave >> 1, wc = wave & 1;
    const int m0 = blockIdx.y * GBM, n0 = blockIdx.x * GBN;

    const int seg = n0 >> 10;
    const float* bsel = (seg == 0) ? bias0 : (seg == 1) ? bias1 : bias2;

    f32x4 acc[4][4] = {};

    const int srow = tid >> 2;
    const int scol = (tid & 3) * 8;
    const u16* Ag0 = A + (size_t)(m0 + srow) * lda + scol;
    const u16* Ag1 = Ag0 + (size_t)64 * lda;
    const u16* Bg0 = BT + (size_t)(n0 + srow) * ldb + scol;
    const u16* Bg1 = Bg0 + (size_t)64 * ldb;
    const int woff = wave << 9;

    // preload tile 0 into buffer 0
    async_ld16(Ag0, As[0] + woff);
    async_ld16(Ag1, As[0] + woff + 64 * GBK);
    async_ld16(Bg0, Bs[0] + woff);
    async_ld16(Bg1, Bs[0] + woff + 64 * GBK);

    int cur = 0;
    for (int kb = 0; kb < K; kb += GBK) {
        __syncthreads();   // buf[cur] loads drained; prior reads of buf[cur^1] done

        if (kb + GBK < K) {
            const int nxt = cur ^ 1;
            async_ld16(Ag0 + kb + GBK, As[nxt] + woff);
            async_ld16(Ag1 + kb + GBK, As[nxt] + woff + 64 * GBK);
            async_ld16(Bg0 + kb + GBK, Bs[nxt] + woff);
            async_ld16(Bg1 + kb + GBK, Bs[nxt] + woff + 64 * GBK);
        }

        short8 af[4], bf[4];
#pragma unroll
        for (int mt = 0; mt < 4; mt++)
            af[mt] = *(const short8*)(As[cur] + (wr * 64 + mt * 16 + l16) * GBK + quad * 8);
#pragma unroll
        for (int nt = 0; nt < 4; nt++)
            bf[nt] = *(const short8*)(Bs[cur] + (wc * 64 + nt * 16 + l16) * GBK + quad * 8);
#pragma unroll
        for (int mt = 0; mt < 4; mt++)
#pragma unroll
            for (int nt = 0; nt < 4; nt++)
                acc[mt][nt] = __builtin_amdgcn_mfma_f32_16x16x32_bf16(
                    af[mt], bf[nt], acc[mt][nt], 0, 0, 0);
        cur ^= 1;
    }

#pragma unroll
    for (int nt = 0; nt < 4; nt++) {
        int col = n0 + wc * 64 + nt * 16 + l16;
        float bv = bsel[col & 1023];
#pragma unroll
        for (int mt = 0; mt < 4; mt++) {
            int row = m0 + wr * 64 + mt * 16 + quad * 4;
#pragma unroll
            for (int r = 0; r < 4; r++)
                store_out(&C[(size_t)(row + r) * ldc + col], acc[mt][nt][r] + bv);
        }
    }
}

// ---------------------------------------------------------------------------
// Flash attention (r11-exact, best measured): BQ=128, 2 q-slabs/wave,
// transposed-MFMA, zero P movement, BKV=128, 2 barriers/iter, no online max.
// ---------------------------------------------------------------------------
#define SEQ 2048
#define BQT 128
#define BKV 128
#define LDK 72     // Ks row: 64 d + 8 pad
#define LDKV 136   // Vs row: 128 kk + 8 pad

__global__ __launch_bounds__(256) void attn(u16* __restrict__ QKV) {
    __shared__ __align__(16) u16 Ks[BKV * LDK];        // [kk][d]
    __shared__ __align__(16) u16 Vs[64 * LDKV];        // [d][kk] (transposed)

    const int tid = threadIdx.x;
    const int wave = tid >> 6, lane = tid & 63;
    const int quad = lane >> 4, l16 = lane & 15;
    const int h = blockIdx.y, bb = blockIdx.z;
    const int q0 = blockIdx.x * BQT;
    const size_t tok0 = (size_t)bb * SEQ;

    const u16* Qb = QKV + tok0 * 3072 + h * 64;
    const u16* Kb = QKV + tok0 * 3072 + 1024 + h * 64;
    const u16* Vb = QKV + tok0 * 3072 + 2048 + h * 64;

    const float cs = 0.18033688011112042f;  // (1/8) * log2(e)

    int qr[2];
    qr[0] = q0 + wave * 16 + l16;
    qr[1] = qr[0] + 64;
    short8 aq[2][2];
#pragma unroll
    for (int s = 0; s < 2; s++) {
        union { short8 v; u16 u[8]; uint32_t w[4]; } qa, qb;
        qa.v = *(const short8*)(Qb + (size_t)qr[s] * 3072 + quad * 8);
        qb.v = *(const short8*)(Qb + (size_t)qr[s] * 3072 + 32 + quad * 8);
#pragma unroll
        for (int j = 0; j < 4; j++) {
            qa.w[j] = pkbf(bf2f(qa.u[2 * j]) * cs, bf2f(qa.u[2 * j + 1]) * cs);
            qb.w[j] = pkbf(bf2f(qb.u[2 * j]) * cs, bf2f(qb.u[2 * j + 1]) * cs);
        }
        aq[s][0] = qa.v; aq[s][1] = qb.v;
    }

    float l_i[2] = {0.0f, 0.0f};
    f32x4 o[2][4] = {};

    const int srow = tid >> 2;           // 0..63
    const int scc = (tid & 3) * 16;      // 0/16/32/48
    const int pr = tid & 63;
    const int dg = wave;

    const u16* kg = Kb + (size_t)srow * 3072 + scc;
    const u16* vg = Vb + (size_t)(2 * pr) * 3072 + dg * 16;

    uint4 k0r = *(const uint4*)(kg);
    uint4 k1r = *(const uint4*)(kg + 8);
    uint4 k2r = *(const uint4*)(kg + (size_t)64 * 3072);
    uint4 k3r = *(const uint4*)(kg + (size_t)64 * 3072 + 8);
    uint4 va0 = *(const uint4*)(vg);
    uint4 va1 = *(const uint4*)(vg + 8);
    uint4 vb0 = *(const uint4*)(vg + 3072);
    uint4 vb1 = *(const uint4*)(vg + 3072 + 8);

    for (int j0 = 0; j0 < SEQ; j0 += BKV) {
        *(uint4*)(Ks + srow * LDK + scc) = k0r;
        *(uint4*)(Ks + srow * LDK + scc + 8) = k1r;
        *(uint4*)(Ks + (srow + 64) * LDK + scc) = k2r;
        *(uint4*)(Ks + (srow + 64) * LDK + scc + 8) = k3r;
        {
            union { uint4 v[2]; u16 u[16]; } a, b;
            a.v[0] = va0; a.v[1] = va1; b.v[0] = vb0; b.v[1] = vb1;
#pragma unroll
            for (int j = 0; j < 16; j++) {
                uint32_t w = (uint32_t)a.u[j] | ((uint32_t)b.u[j] << 16);
                *(uint32_t*)(Vs + (dg * 16 + j) * LDKV + 2 * pr) = w;
            }
        }
        __syncthreads();   // B1: staged tile visible

        if (j0 + BKV < SEQ) {
            size_t off = (size_t)(j0 + BKV) * 3072;
            k0r = *(const uint4*)(kg + off);
            k1r = *(const uint4*)(kg + off + 8);
            k2r = *(const uint4*)(kg + off + (size_t)64 * 3072);
            k3r = *(const uint4*)(kg + off + (size_t)64 * 3072 + 8);
            va0 = *(const uint4*)(vg + off);
            va1 = *(const uint4*)(vg + off + 8);
            vb0 = *(const uint4*)(vg + off + 3072);
            vb1 = *(const uint4*)(vg + off + 3072 + 8);
        }

        f32x4 st[2][8];
#pragma unroll
        for (int kkt = 0; kkt < 8; kkt++) {
            f32x4 s0 = {}, s1 = {};
#pragma unroll
            for (int k2 = 0; k2 < 2; k2++) {
                short8 ak = *(const short8*)(Ks + (kkt * 16 + l16) * LDK + k2 * 32 + quad * 8);
                s0 = __builtin_amdgcn_mfma_f32_16x16x32_bf16(ak, aq[0][k2], s0, 0, 0, 0);
                s1 = __builtin_amdgcn_mfma_f32_16x16x32_bf16(ak, aq[1][k2], s1, 0, 0, 0);
            }
            st[0][kkt] = s0; st[1][kkt] = s1;
        }

#pragma unroll
        for (int s = 0; s < 2; s++) {
            float ls = 0.0f;
#pragma unroll
            for (int kkt = 0; kkt < 8; kkt++)
#pragma unroll
                for (int r = 0; r < 4; r++) {
                    st[s][kkt][r] = __builtin_amdgcn_exp2f(st[s][kkt][r]);
                    ls += st[s][kkt][r];
                }
            ls += __shfl_xor(ls, 16, 64);
            ls += __shfl_xor(ls, 32, 64);
            l_i[s] += ls;
        }

#pragma unroll
        for (int kkt = 0; kkt < 8; kkt++) {
            union { uint32_t w[2]; s4v s; } bp0, bp1;
            bp0.w[0] = pkbf(st[0][kkt][0], st[0][kkt][1]);
            bp0.w[1] = pkbf(st[0][kkt][2], st[0][kkt][3]);
            bp1.w[0] = pkbf(st[1][kkt][0], st[1][kkt][1]);
            bp1.w[1] = pkbf(st[1][kkt][2], st[1][kkt][3]);
#pragma unroll
            for (int dt = 0; dt < 4; dt++) {
                s4v av = *(const s4v*)(Vs + (dt * 16 + l16) * LDKV + kkt * 16 + quad * 4);
                o[0][dt] = __builtin_amdgcn_mfma_f32_16x16x16bf16_1k(av, bp0.s, o[0][dt], 0, 0, 0);
                o[1][dt] = __builtin_amdgcn_mfma_f32_16x16x16bf16_1k(av, bp1.s, o[1][dt], 0, 0, 0);
            }
        }

        __syncthreads();   // B2: Ks/Vs reads done before next staging
    }

#pragma unroll
    for (int s = 0; s < 2; s++) {
        const float inv_l = 1.0f / l_i[s];
        u16* orow = QKV + (tok0 + qr[s]) * 3072 + h * 64;
#pragma unroll
        for (int dt = 0; dt < 4; dt++) {
            uint32_t w0 = pkbf(o[s][dt][0] * inv_l, o[s][dt][1] * inv_l);
            uint32_t w1 = pkbf(o[s][dt][2] * inv_l, o[s][dt][3] * inv_l);
            uint2 w = {w0, w1};
            *(uint2*)(orow + dt * 16 + quad * 4) = w;
        }
    }
}

// ---------------------------------------------------------------------------
extern "C" void kernel_launch(void* const* d_in, const int* in_sizes, int n_in,
                              void* d_out, int out_size, void* d_ws, size_t ws_size,
                              hipStream_t stream) {
    const float* x  = (const float*)d_in[0];
    const float* wq = (const float*)d_in[1];
    const float* bq = (const float*)d_in[2];
    const float* wk = (const float*)d_in[3];
    const float* bk = (const float*)d_in[4];
    const float* wv = (const float*)d_in[5];
    const float* bv = (const float*)d_in[6];
    const float* wo = (const float*)d_in[7];
    const float* bo = (const float*)d_in[8];
    (void)in_sizes; (void)n_in; (void)out_size; (void)ws_size;

    u16* QKV = (u16*)d_ws;                              // [4096][3072] bf16, 24 MB
    u16* wT  = QKV + (size_t)4096 * 3072;               // [3][1024][1024] bf16, 6 MB
    u16* xb  = wT + (size_t)3 * 1024 * 1024;            // [4096][1024] bf16, 8 MB
    u16* woT = xb;                                      // reuses xb after gemm1

    prep<<<dim3(32, 32, 5), dim3(32, 8), 0, stream>>>(x, wq, wk, wv, xb, wT);
    gemm_bt<u16><<<dim3(24, 32), 256, 0, stream>>>(xb, 1024, wT, 1024, bq, bk, bv,
                                                   QKV, 3072, 1024);
    transpose1<<<dim3(32, 32), dim3(32, 8), 0, stream>>>(wo, woT);
    attn<<<dim3(16, 16, 2), 256, 0, stream>>>(QKV);
    gemm_bt<float><<<dim3(8, 32), 256, 0, stream>>>(QKV, 3072, woT, 1024, bo, bo, bo,
                                                    (float*)d_out, 1024, 1024);
}